// Round 7
// baseline (301.591 us; speedup 1.0000x reference)
//
#include <hip/hip_runtime.h>

#define H 8
#define D 32
#define HD 256
#define NEG_SLOPE 0.2f
#define SCB 1024

typedef __attribute__((ext_vector_type(8))) short bf8;
typedef __attribute__((ext_vector_type(4))) float f4;

// fp32 -> bf16 (round-to-nearest-even), integer path
__device__ __forceinline__ unsigned short f2b(float x) {
    unsigned u = __float_as_uint(x);
    unsigned r = (u + 0x7fffu + ((u >> 16) & 1u)) >> 16;
    return (unsigned short)r;
}

// k0: W transpose->bf16 | M_e (8x8) | cnt zero.  (replaces memset + prep)
__global__ __launch_bounds__(256) void k0(
        const float* __restrict__ W, unsigned short* __restrict__ Wtb,
        const float* __restrict__ W_e, const float* __restrict__ attn_e,
        float* __restrict__ M, int* __restrict__ cnt, int N) {
    const int b = blockIdx.x, t = threadIdx.x;
    if (b < HD) {                          // ---- W transpose ----
        Wtb[b * HD + t] = f2b(W[t * HD + b]);
    } else if (b == HD) {                  // ---- M_e ----
        if (t < 64) {
            int k = t >> 3, hh = t & 7;
            float acc = 0.f;
            for (int d = 0; d < D; ++d)
                acc = fmaf(W_e[k * HD + hh * D + d], attn_e[hh * D + d], acc);
            M[k * 8 + hh] = acc;
        }
    } else {                               // ---- cnt zero ----
        int i = (b - HD - 1) * 256 + t;
        if (i < N) cnt[i] = 0;
    }
}

// parallel exclusive scan, step 1: block-local scan + block totals
__global__ __launch_bounds__(1024) void k_scan1(const int* __restrict__ cnt,
                                                int* __restrict__ offs,
                                                int* __restrict__ btot, int N) {
    __shared__ int wtot[16], wbase[16];
    const int t = threadIdx.x, wid = t >> 6, lane = t & 63;
    int i = blockIdx.x * SCB + t;
    int v = (i < N) ? cnt[i] : 0;
    int x = v;
#pragma unroll
    for (int off = 1; off < 64; off <<= 1) {
        int y = __shfl_up(x, off, 64);
        if (lane >= off) x += y;
    }
    if (lane == 63) wtot[wid] = x;
    __syncthreads();
    if (t < 16) {
        int w = wtot[t], xs = w;
#pragma unroll
        for (int off = 1; off < 16; off <<= 1) {
            int y = __shfl_up(xs, off, 64);
            if (t >= off) xs += y;
        }
        wbase[t] = xs - w;
        if (t == 15) btot[blockIdx.x] = xs;
    }
    __syncthreads();
    if (i < N) offs[i] = wbase[wid] + (x - v);
}

// step 2 (fused scan2+scan3): wave 0 re-scans the <=64 block totals, then the
// whole block adds its base; cur initialized for k_edge's atomic slot-grab.
__global__ __launch_bounds__(1024) void k_scan3(int* __restrict__ offs,
                                                const int* __restrict__ btot,
                                                int* __restrict__ cur,
                                                int N, int E, int nb) {
    __shared__ int bb;
    const int t = threadIdx.x;
    if (t < 64) {
        int vv = (t < nb) ? btot[t] : 0;
        int x = vv;
#pragma unroll
        for (int off = 1; off < 64; off <<= 1) {
            int y = __shfl_up(x, off, 64);
            if (t >= off) x += y;
        }
        if (t == blockIdx.x) bb = x - vv;   // exclusive base for this block
    }
    __syncthreads();
    const int i = blockIdx.x * SCB + t;
    if (i < N) {
        const int o = offs[i] + bb;
        offs[i] = o;
        cur[i] = o;
    }
    if (i == 0) offs[N] = E;
}

// fused dispatch, 512 threads:
//  [0,bg)    : MFMA GEMM, 8 waves x 16 rows, Wt LDS-staged (bank-swizzled).
//  [bg,...)  : dst histogram (atomicAdd cnt), 4 edges/thread, overlapped
//              under the GEMM (independent inputs).
__global__ __launch_bounds__(512) void k_fuse(
        const float* __restrict__ feat, const unsigned short* __restrict__ Wtb,
        const float* __restrict__ attn_l, const float* __restrict__ attn_r,
        unsigned short* __restrict__ hb, float* __restrict__ el,
        float* __restrict__ er, int N, int bg,
        const int* __restrict__ dst, int* __restrict__ cnt, int E) {
    const int t = threadIdx.x;
    if (blockIdx.x >= bg) {                // ---- histogram ----
        const int base = (blockIdx.x - bg) * 2048;
        const int end = min(base + 2048, E);
        for (int e = base + t; e < end; e += 512)
            atomicAdd(&cnt[dst[e]], 1);
        return;
    }
    __shared__ unsigned short lwt[128 * HD];   // 64 KB: half of Wt, swizzled
    const int l = t & 63, wv = t >> 6;
    const int row0 = (blockIdx.x * 8 + wv) * 16;
    const bool act = row0 < N;             // tail waves stage+barrier only
    const int m = l & 15, q = l >> 4;

    // preload all 8 A-fragments (row = row0+m), f32 -> bf16 in-register
    bf8 afr[8];
    if (act) {
        const float* arow = feat + (size_t)(row0 + m) * HD + q * 8;
#pragma unroll
        for (int kc = 0; kc < 8; ++kc) {
            const float4 f0 = *(const float4*)(arow + kc * 32);
            const float4 f1 = *(const float4*)(arow + kc * 32 + 4);
            bf8 a;
            a[0] = (short)f2b(f0.x); a[1] = (short)f2b(f0.y);
            a[2] = (short)f2b(f0.z); a[3] = (short)f2b(f0.w);
            a[4] = (short)f2b(f1.x); a[5] = (short)f2b(f1.y);
            a[6] = (short)f2b(f1.z); a[7] = (short)f2b(f1.w);
            afr[kc] = a;
        }
    }

    f4 acc[16];
#pragma unroll
    for (int nt = 0; nt < 16; ++nt) acc[nt] = (f4){0.f, 0.f, 0.f, 0.f};

    const uint4* wt4 = (const uint4*)Wtb;
    uint4* l4 = (uint4*)lwt;
#pragma unroll
    for (int half = 0; half < 2; ++half) {
        if (half) __syncthreads();         // all waves done reading half 0
        // stage 64KB chunk: dest uint4 index u ^ (row&7)  (row = u>>5)
#pragma unroll
        for (int i = 0; i < 8; ++i) {
            const int u = i * 512 + t;
            l4[u ^ ((u >> 5) & 7)] = wt4[half * 4096 + u];
        }
        __syncthreads();
        if (act) {
#pragma unroll
            for (int ntl = 0; ntl < 8; ++ntl) {
                const int nt = half * 8 + ntl;
                const int lc = ntl * 16 + m;          // chunk-local Wt row
                const unsigned short* bp = lwt + lc * HD;
                const int sw = (lc & 7) * 8;          // swizzle, ushort units
#pragma unroll
                for (int kc = 0; kc < 8; ++kc) {
                    const bf8 b = *(const bf8*)(bp + ((q * 8 + kc * 32) ^ sw));
                    acc[nt] = __builtin_amdgcn_mfma_f32_16x16x32_bf16(
                                  afr[kc], b, acc[nt], 0, 0, 0);
                }
            }
        }
    }
    if (!act) return;

    // epilogue: C/D layout col = l&15, row = q*4+reg.  Store hb; full el/er
    // per row via width-16 butterflies.
#pragma unroll
    for (int h = 0; h < H; ++h) {
        float elp[4] = {0.f, 0.f, 0.f, 0.f};
        float erp[4] = {0.f, 0.f, 0.f, 0.f};
#pragma unroll
        for (int s = 0; s < 2; ++s) {
            const int nt = h * 2 + s;
            const int c = nt * 16 + m;
            const float alc = attn_l[c];
            const float arc = attn_r[c];
#pragma unroll
            for (int reg = 0; reg < 4; ++reg) {
                const float v = acc[nt][reg];
                hb[(size_t)(row0 + q * 4 + reg) * HD + c] = f2b(v);
                elp[reg] = fmaf(v, alc, elp[reg]);
                erp[reg] = fmaf(v, arc, erp[reg]);
            }
        }
#pragma unroll
        for (int reg = 0; reg < 4; ++reg) {
#pragma unroll
            for (int off = 1; off < 16; off <<= 1) {
                elp[reg] += __shfl_xor(elp[reg], off, 16);
                erp[reg] += __shfl_xor(erp[reg], off, 16);
            }
        }
        if (m == 0) {
#pragma unroll
            for (int reg = 0; reg < 4; ++reg) {
                el[(row0 + q * 4 + reg) * H + h] = elp[reg];
                er[(row0 + q * 4 + reg) * H + h] = erp[reg];
            }
        }
    }
}

// k_edge: per edge, compute lg8 = el[src] + ee.M (coalesced edge_emb read),
// grab CSR slot via atomic cur, write src_csr + lgcsr[slot][8] (f32).
// Moves all random p-phase loads out of k_node.
__global__ __launch_bounds__(256) void k_edge(
        const int* __restrict__ src, const int* __restrict__ dst,
        const float* __restrict__ edge_emb, const float* __restrict__ el,
        const float* __restrict__ Mg, int* __restrict__ cur,
        int* __restrict__ src_csr, float* __restrict__ lgcsr, int E) {
    const int t = threadIdx.x;
    float Mreg[8][8];
#pragma unroll
    for (int k = 0; k < 8; ++k) {
        const float4 m0 = *(const float4*)(Mg + k * 8);
        const float4 m1 = *(const float4*)(Mg + k * 8 + 4);
        Mreg[k][0] = m0.x; Mreg[k][1] = m0.y; Mreg[k][2] = m0.z; Mreg[k][3] = m0.w;
        Mreg[k][4] = m1.x; Mreg[k][5] = m1.y; Mreg[k][6] = m1.z; Mreg[k][7] = m1.w;
    }
    const int base = blockIdx.x * 1024;
    const int end = min(base + 1024, E);
    for (int e = base + t; e < end; e += 256) {
        const int se = src[e], de = dst[e];
        const float4 e0 = ((const float4*)edge_emb)[e * 2];
        const float4 e1 = ((const float4*)edge_emb)[e * 2 + 1];
        const float4 l0 = ((const float4*)el)[se * 2];
        const float4 l1 = ((const float4*)el)[se * 2 + 1];
        const float ee[8] = {e0.x, e0.y, e0.z, e0.w, e1.x, e1.y, e1.z, e1.w};
        const float ela[8] = {l0.x, l0.y, l0.z, l0.w, l1.x, l1.y, l1.z, l1.w};
        float lg[8];
#pragma unroll
        for (int hh = 0; hh < 8; ++hh) {
            float x = ela[hh];
#pragma unroll
            for (int k = 0; k < 8; ++k)
                x = fmaf(ee[k], Mreg[k][hh], x);
            lg[hh] = x;
        }
        const int p = atomicAdd(&cur[de], 1);
        src_csr[p] = se;
        float4* o = (float4*)&lgcsr[(size_t)p * 8];
        o[0] = make_float4(lg[0], lg[1], lg[2], lg[3]);
        o[1] = make_float4(lg[4], lg[5], lg[6], lg[7]);
    }
}

// aggregation v4: ONE WAVE per node, zero LDS/barriers.
//  p-phase: 8 COALESCED dword loads/tile (lgcsr in CSR order), +er, lrelu, exp.
//  agg: dual-edge uint4 gather with MANUAL 8-deep load staging (w8[8]) so 8
//  independent 512B row fetches are in flight per wave.
__global__ __launch_bounds__(256) void k_node(
        const int* __restrict__ offs, const int* __restrict__ src_csr,
        const float* __restrict__ lgcsr, const float* __restrict__ er,
        const unsigned short* __restrict__ hb, const float* __restrict__ bias,
        float* __restrict__ out, int N) {
    const int t = threadIdx.x;
    const int lane = t & 63;
    const int v = blockIdx.x * 4 + (t >> 6);
    if (v >= N) return;
    const int hh = lane & 7;        // p-phase: head
    const int sl = lane & 31;       // col-chunk slot (8 cols = 16B)
    const int half = lane >> 5;     // edge parity
    const int cb = sl * 8;
    const int hq = sl >> 2;         // head of this chunk
    const int s0 = offs[v];
    const int deg = offs[v + 1] - s0;

    const float erv = er[(size_t)v * 8 + hh];
    const unsigned short* hbc = hb + cb;

    float a[8];
#pragma unroll
    for (int i = 0; i < 8; ++i) a[i] = 0.f;
    float psum = 0.f;

    for (int j0 = 0; j0 < deg; j0 += 64) {
        const int nj = min(64, deg - j0);
        int srcl = 0;
        if (lane < nj) srcl = src_csr[s0 + j0 + lane];
        const float* lgb = lgcsr + (size_t)(s0 + j0) * 8;

        // ---- p-phase: coalesced logit loads (lane covers slot s*8+(lane>>3),
        // head lane&7 -> float offset s*64+lane) ----
        float pv[8];
#pragma unroll
        for (int s = 0; s < 8; ++s) {
            pv[s] = 0.f;
            if (s * 8 < nj) {                       // wave-uniform
                const int j = s * 8 + (lane >> 3);
                if (j < nj) {
                    float x = lgb[s * 64 + lane] + erv;
                    x = (x >= 0.f) ? x : NEG_SLOPE * x;
                    pv[s] = __expf(x);              // no max-sub: |logit| small
                    psum += pv[s];
                }
            }
        }

        // ---- aggregation: 2 edges/load, 8 loads staged per group ----
#pragma unroll
        for (int g = 0; g < 4; ++g) {
            if (g * 16 >= nj) break;                // wave-uniform
            int sx8[8];
            uint4 w8[8];
#pragma unroll
            for (int i = 0; i < 8; ++i) {
                const int s = 2 * g + (i >> 2);
                const int jj = 2 * (i & 3) + half;
                sx8[i] = __shfl(srcl, s * 8 + jj, 64);
                w8[i] = *(const uint4*)(hbc + (size_t)sx8[i] * HD);
            }
#pragma unroll
            for (int i = 0; i < 8; ++i) {
                const int s = 2 * g + (i >> 2);
                const int jj = 2 * (i & 3) + half;
                const float pj = __shfl(pv[s], jj * 8 + hq, 64);  // 0 if j>=nj
                const uint4 w = w8[i];
                a[0] = fmaf(pj, __uint_as_float(w.x << 16), a[0]);
                a[1] = fmaf(pj, __uint_as_float(w.x & 0xffff0000u), a[1]);
                a[2] = fmaf(pj, __uint_as_float(w.y << 16), a[2]);
                a[3] = fmaf(pj, __uint_as_float(w.y & 0xffff0000u), a[3]);
                a[4] = fmaf(pj, __uint_as_float(w.z << 16), a[4]);
                a[5] = fmaf(pj, __uint_as_float(w.z & 0xffff0000u), a[5]);
                a[6] = fmaf(pj, __uint_as_float(w.w << 16), a[6]);
                a[7] = fmaf(pj, __uint_as_float(w.w & 0xffff0000u), a[7]);
            }
        }
    }

    // merge edge-parity halves (same cols, disjoint edge subsets)
#pragma unroll
    for (int i = 0; i < 8; ++i) a[i] += __shfl_xor(a[i], 32, 64);

    // per-head sum of p, deferred normalization
    psum += __shfl_xor(psum, 8, 64);
    psum += __shfl_xor(psum, 16, 64);
    psum += __shfl_xor(psum, 32, 64);
    const float rs = 1.f / (__shfl(psum, hq, 8) + 1e-9f);
    if (half == 0) {
        const float4 b0 = *(const float4*)&bias[cb];
        const float4 b1 = *(const float4*)&bias[cb + 4];
        *(float4*)&out[(size_t)v * HD + cb] =
            make_float4(fmaf(a[0], rs, b0.x), fmaf(a[1], rs, b0.y),
                        fmaf(a[2], rs, b0.z), fmaf(a[3], rs, b0.w));
        *(float4*)&out[(size_t)v * HD + cb + 4] =
            make_float4(fmaf(a[4], rs, b1.x), fmaf(a[5], rs, b1.y),
                        fmaf(a[6], rs, b1.z), fmaf(a[7], rs, b1.w));
    }
}

extern "C" void kernel_launch(void* const* d_in, const int* in_sizes, int n_in,
                              void* d_out, int out_size, void* d_ws, size_t ws_size,
                              hipStream_t stream) {
    const float* feat     = (const float*)d_in[0];
    const float* edge_emb = (const float*)d_in[1];
    const int*   src      = (const int*)d_in[2];
    const int*   dst      = (const int*)d_in[3];
    const float* W_src    = (const float*)d_in[4];
    const float* W_e      = (const float*)d_in[5];
    const float* attn_l   = (const float*)d_in[6];
    const float* attn_r   = (const float*)d_in[7];
    const float* attn_e   = (const float*)d_in[8];
    const float* bias     = (const float*)d_in[9];
    float* out = (float*)d_out;

    const int N = in_sizes[0] / HD;
    const int E = in_sizes[2];

    char* ws = (char*)d_ws;
    unsigned short* hb = (unsigned short*)ws; ws += (size_t)N * HD * 2;   // 25.6MB
    float* lgcsr = (float*)ws; ws += (size_t)E * H * 4;                   // 25.6MB
    int* src_csr = (int*)ws; ws += (size_t)E * 4;                         // 3.2MB
    float* el   = (float*)ws; ws += (size_t)N * H * 4;
    float* er   = (float*)ws; ws += (size_t)N * H * 4;
    int*   cnt  = (int*)ws;   ws += (size_t)N * 4;   // dead after scan1 ->
    int*   cur  = cnt;                               // cur aliases cnt
    int* offs   = (int*)ws; ws += (size_t)(N + 1) * 4;
    unsigned short* Wtb = (unsigned short*)ws; ws += (size_t)HD * HD * 2;
    int* btot  = (int*)ws; ws += 64 * 4;
    float* M   = (float*)ws; ws += 256;

    const int nz  = (N + 255) / 256;
    const int nsb = (N + SCB - 1) / SCB;       // <= 64
    const int bg  = ((N + 15) / 16 + 7) / 8;   // gemm blocks (8 waves each)
    const int bhist = (E + 2047) / 2048;       // histogram blocks (ILP-4)

    k0      <<<HD + 1 + nz, 256, 0, stream>>>(W_src, Wtb, W_e, attn_e, M, cnt, N);
    k_fuse  <<<bg + bhist, 512, 0, stream>>>(feat, Wtb, attn_l, attn_r, hb, el, er,
                                             N, bg, dst, cnt, E);
    k_scan1 <<<nsb, SCB, 0, stream>>>(cnt, offs, btot, N);
    k_scan3 <<<nsb, SCB, 0, stream>>>(offs, btot, cur, N, E, nsb);
    k_edge  <<<(E + 1023) / 1024, 256, 0, stream>>>(src, dst, edge_emb, el, M,
                                                    cur, src_csr, lgcsr, E);
    k_node  <<<(N + 3) / 4, 256, 0, stream>>>(offs, src_csr, lgcsr, er,
                                              hb, bias, out, N);
}

// Round 8
// 282.221 us; speedup vs baseline: 1.0686x; 1.0686x over previous
//
#include <hip/hip_runtime.h>

#define H 8
#define D 32
#define HD 256
#define NEG_SLOPE 0.2f
#define SCB 1024

typedef __attribute__((ext_vector_type(8))) short bf8;
typedef __attribute__((ext_vector_type(4))) float f4;

// fp32 -> bf16 (round-to-nearest-even), integer path
__device__ __forceinline__ unsigned short f2b(float x) {
    unsigned u = __float_as_uint(x);
    unsigned r = (u + 0x7fffu + ((u >> 16) & 1u)) >> 16;
    return (unsigned short)r;
}

// k0: W transpose->bf16 | M_e (8x8) | cnt zero.
__global__ __launch_bounds__(256) void k0(
        const float* __restrict__ W, unsigned short* __restrict__ Wtb,
        const float* __restrict__ W_e, const float* __restrict__ attn_e,
        float* __restrict__ M, int* __restrict__ cnt, int N) {
    const int b = blockIdx.x, t = threadIdx.x;
    if (b < HD) {                          // ---- W transpose ----
        Wtb[b * HD + t] = f2b(W[t * HD + b]);
    } else if (b == HD) {                  // ---- M_e ----
        if (t < 64) {
            int k = t >> 3, hh = t & 7;
            float acc = 0.f;
            for (int d = 0; d < D; ++d)
                acc = fmaf(W_e[k * HD + hh * D + d], attn_e[hh * D + d], acc);
            M[k * 8 + hh] = acc;
        }
    } else {                               // ---- cnt zero ----
        int i = (b - HD - 1) * 256 + t;
        if (i < N) cnt[i] = 0;
    }
}

// parallel exclusive scan, step 1: block-local scan + block totals
__global__ __launch_bounds__(1024) void k_scan1(const int* __restrict__ cnt,
                                                int* __restrict__ offs,
                                                int* __restrict__ btot, int N) {
    __shared__ int wtot[16], wbase[16];
    const int t = threadIdx.x, wid = t >> 6, lane = t & 63;
    int i = blockIdx.x * SCB + t;
    int v = (i < N) ? cnt[i] : 0;
    int x = v;
#pragma unroll
    for (int off = 1; off < 64; off <<= 1) {
        int y = __shfl_up(x, off, 64);
        if (lane >= off) x += y;
    }
    if (lane == 63) wtot[wid] = x;
    __syncthreads();
    if (t < 16) {
        int w = wtot[t], xs = w;
#pragma unroll
        for (int off = 1; off < 16; off <<= 1) {
            int y = __shfl_up(xs, off, 64);
            if (t >= off) xs += y;
        }
        wbase[t] = xs - w;
        if (t == 15) btot[blockIdx.x] = xs;
    }
    __syncthreads();
    if (i < N) offs[i] = wbase[wid] + (x - v);
}

// step 2 (fused scan2+scan3): wave 0 re-scans the <=64 block totals, then the
// whole block adds its base.  (cur eliminated: k_edge uses offs+ord.)
__global__ __launch_bounds__(1024) void k_scan3(int* __restrict__ offs,
                                                const int* __restrict__ btot,
                                                int N, int E, int nb) {
    __shared__ int bb;
    const int t = threadIdx.x;
    if (t < 64) {
        int vv = (t < nb) ? btot[t] : 0;
        int x = vv;
#pragma unroll
        for (int off = 1; off < 64; off <<= 1) {
            int y = __shfl_up(x, off, 64);
            if (t >= off) x += y;
        }
        if (t == blockIdx.x) bb = x - vv;   // exclusive base for this block
    }
    __syncthreads();
    const int i = blockIdx.x * SCB + t;
    if (i < N) offs[i] += bb;
    if (i == 0) offs[N] = E;
}

// fused dispatch, 512 threads:
//  [0,bg)    : MFMA GEMM, 8 waves x 16 rows, Wt LDS-staged (bank-swizzled).
//  [bg,...)  : dst histogram + per-edge ordinal (atomicAdd cnt), overlapped
//              under the GEMM (independent inputs).
__global__ __launch_bounds__(512) void k_fuse(
        const float* __restrict__ feat, const unsigned short* __restrict__ Wtb,
        const float* __restrict__ attn_l, const float* __restrict__ attn_r,
        unsigned short* __restrict__ hb, float* __restrict__ el,
        float* __restrict__ er, int N, int bg,
        const int* __restrict__ dst, int* __restrict__ cnt,
        int* __restrict__ ord, int E) {
    const int t = threadIdx.x;
    if (blockIdx.x >= bg) {                // ---- histogram + ordinal ----
        const int base = (blockIdx.x - bg) * 2048;
        const int end = min(base + 2048, E);
        for (int e = base + t; e < end; e += 512)
            ord[e] = atomicAdd(&cnt[dst[e]], 1);
        return;
    }
    __shared__ unsigned short lwt[128 * HD];   // 64 KB: half of Wt, swizzled
    const int l = t & 63, wv = t >> 6;
    const int row0 = (blockIdx.x * 8 + wv) * 16;
    const bool act = row0 < N;             // tail waves stage+barrier only
    const int m = l & 15, q = l >> 4;

    // preload all 8 A-fragments (row = row0+m), f32 -> bf16 in-register
    bf8 afr[8];
    if (act) {
        const float* arow = feat + (size_t)(row0 + m) * HD + q * 8;
#pragma unroll
        for (int kc = 0; kc < 8; ++kc) {
            const float4 f0 = *(const float4*)(arow + kc * 32);
            const float4 f1 = *(const float4*)(arow + kc * 32 + 4);
            bf8 a;
            a[0] = (short)f2b(f0.x); a[1] = (short)f2b(f0.y);
            a[2] = (short)f2b(f0.z); a[3] = (short)f2b(f0.w);
            a[4] = (short)f2b(f1.x); a[5] = (short)f2b(f1.y);
            a[6] = (short)f2b(f1.z); a[7] = (short)f2b(f1.w);
            afr[kc] = a;
        }
    }

    f4 acc[16];
#pragma unroll
    for (int nt = 0; nt < 16; ++nt) acc[nt] = (f4){0.f, 0.f, 0.f, 0.f};

    const uint4* wt4 = (const uint4*)Wtb;
    uint4* l4 = (uint4*)lwt;
#pragma unroll
    for (int half = 0; half < 2; ++half) {
        if (half) __syncthreads();         // all waves done reading half 0
        // stage 64KB chunk: dest uint4 index u ^ (row&7)  (row = u>>5)
#pragma unroll
        for (int i = 0; i < 8; ++i) {
            const int u = i * 512 + t;
            l4[u ^ ((u >> 5) & 7)] = wt4[half * 4096 + u];
        }
        __syncthreads();
        if (act) {
#pragma unroll
            for (int ntl = 0; ntl < 8; ++ntl) {
                const int nt = half * 8 + ntl;
                const int lc = ntl * 16 + m;          // chunk-local Wt row
                const unsigned short* bp = lwt + lc * HD;
                const int sw = (lc & 7) * 8;          // swizzle, ushort units
#pragma unroll
                for (int kc = 0; kc < 8; ++kc) {
                    const bf8 b = *(const bf8*)(bp + ((q * 8 + kc * 32) ^ sw));
                    acc[nt] = __builtin_amdgcn_mfma_f32_16x16x32_bf16(
                                  afr[kc], b, acc[nt], 0, 0, 0);
                }
            }
        }
    }
    if (!act) return;

    // epilogue: C/D layout col = l&15, row = q*4+reg.  Store hb; full el/er
    // per row via width-16 butterflies.
#pragma unroll
    for (int h = 0; h < H; ++h) {
        float elp[4] = {0.f, 0.f, 0.f, 0.f};
        float erp[4] = {0.f, 0.f, 0.f, 0.f};
#pragma unroll
        for (int s = 0; s < 2; ++s) {
            const int nt = h * 2 + s;
            const int c = nt * 16 + m;
            const float alc = attn_l[c];
            const float arc = attn_r[c];
#pragma unroll
            for (int reg = 0; reg < 4; ++reg) {
                const float v = acc[nt][reg];
                hb[(size_t)(row0 + q * 4 + reg) * HD + c] = f2b(v);
                elp[reg] = fmaf(v, alc, elp[reg]);
                erp[reg] = fmaf(v, arc, erp[reg]);
            }
        }
#pragma unroll
        for (int reg = 0; reg < 4; ++reg) {
#pragma unroll
            for (int off = 1; off < 16; off <<= 1) {
                elp[reg] += __shfl_xor(elp[reg], off, 16);
                erp[reg] += __shfl_xor(erp[reg], off, 16);
            }
        }
        if (m == 0) {
#pragma unroll
            for (int reg = 0; reg < 4; ++reg) {
                el[(row0 + q * 4 + reg) * H + h] = elp[reg];
                er[(row0 + q * 4 + reg) * H + h] = erp[reg];
            }
        }
    }
}

// k_edge: per edge, lg8 = el[src] + ee.M (coalesced edge_emb read), write to
// CSR slot offs[dst]+ord (atomic-free).  1 edge/thread, max TLP.
__global__ __launch_bounds__(256) void k_edge(
        const int* __restrict__ src, const int* __restrict__ dst,
        const float* __restrict__ edge_emb, const float* __restrict__ el,
        const float* __restrict__ Mg, const int* __restrict__ offs,
        const int* __restrict__ ord,
        int* __restrict__ src_csr, float* __restrict__ lgcsr, int E) {
    const int e = blockIdx.x * 256 + threadIdx.x;
    if (e >= E) return;
    const int se = src[e], de = dst[e];
    const float4 e0 = ((const float4*)edge_emb)[e * 2];
    const float4 e1 = ((const float4*)edge_emb)[e * 2 + 1];
    const float4 l0 = ((const float4*)el)[se * 2];
    const float4 l1 = ((const float4*)el)[se * 2 + 1];
    const float ee[8] = {e0.x, e0.y, e0.z, e0.w, e1.x, e1.y, e1.z, e1.w};
    const float ela[8] = {l0.x, l0.y, l0.z, l0.w, l1.x, l1.y, l1.z, l1.w};
    float lg[8];
#pragma unroll
    for (int hh = 0; hh < 8; ++hh) {
        float x = ela[hh];
#pragma unroll
        for (int k = 0; k < 8; ++k)
            x = fmaf(ee[k], Mg[k * 8 + hh], x);   // Mg uniform -> s-loads
        lg[hh] = x;
    }
    const int p = offs[de] + ord[e];
    src_csr[p] = se;
    float4* o = (float4*)&lgcsr[(size_t)p * 8];
    o[0] = make_float4(lg[0], lg[1], lg[2], lg[3]);
    o[1] = make_float4(lg[4], lg[5], lg[6], lg[7]);
}

// aggregation: ONE WAVE per node, zero LDS/barriers.
//  p-phase: 8 COALESCED dword loads/tile (lgcsr in CSR order), +er, lrelu, exp.
//  agg: dual-edge uint4 gather with MANUAL 8-deep load staging (w8[8]).
__global__ __launch_bounds__(256) void k_node(
        const int* __restrict__ offs, const int* __restrict__ src_csr,
        const float* __restrict__ lgcsr, const float* __restrict__ er,
        const unsigned short* __restrict__ hb, const float* __restrict__ bias,
        float* __restrict__ out, int N) {
    const int t = threadIdx.x;
    const int lane = t & 63;
    const int v = blockIdx.x * 4 + (t >> 6);
    if (v >= N) return;
    const int hh = lane & 7;        // p-phase: head
    const int sl = lane & 31;       // col-chunk slot (8 cols = 16B)
    const int half = lane >> 5;     // edge parity
    const int cb = sl * 8;
    const int hq = sl >> 2;         // head of this chunk
    const int s0 = offs[v];
    const int deg = offs[v + 1] - s0;

    const float erv = er[(size_t)v * 8 + hh];
    const unsigned short* hbc = hb + cb;

    float a[8];
#pragma unroll
    for (int i = 0; i < 8; ++i) a[i] = 0.f;
    float psum = 0.f;

    for (int j0 = 0; j0 < deg; j0 += 64) {
        const int nj = min(64, deg - j0);
        int srcl = 0;
        if (lane < nj) srcl = src_csr[s0 + j0 + lane];
        const float* lgb = lgcsr + (size_t)(s0 + j0) * 8;

        // ---- p-phase: coalesced logit loads ----
        float pv[8];
#pragma unroll
        for (int s = 0; s < 8; ++s) {
            pv[s] = 0.f;
            if (s * 8 < nj) {                       // wave-uniform
                const int j = s * 8 + (lane >> 3);
                if (j < nj) {
                    float x = lgb[s * 64 + lane] + erv;
                    x = (x >= 0.f) ? x : NEG_SLOPE * x;
                    pv[s] = __expf(x);              // no max-sub: |logit| small
                    psum += pv[s];
                }
            }
        }

        // ---- aggregation: 2 edges/load, 8 loads staged per group ----
#pragma unroll
        for (int g = 0; g < 4; ++g) {
            if (g * 16 >= nj) break;                // wave-uniform
            int sx8[8];
            uint4 w8[8];
#pragma unroll
            for (int i = 0; i < 8; ++i) {
                const int s = 2 * g + (i >> 2);
                const int jj = 2 * (i & 3) + half;
                sx8[i] = __shfl(srcl, s * 8 + jj, 64);
                w8[i] = *(const uint4*)(hbc + (size_t)sx8[i] * HD);
            }
#pragma unroll
            for (int i = 0; i < 8; ++i) {
                const int s = 2 * g + (i >> 2);
                const int jj = 2 * (i & 3) + half;
                const float pj = __shfl(pv[s], jj * 8 + hq, 64);  // 0 if j>=nj
                const uint4 w = w8[i];
                a[0] = fmaf(pj, __uint_as_float(w.x << 16), a[0]);
                a[1] = fmaf(pj, __uint_as_float(w.x & 0xffff0000u), a[1]);
                a[2] = fmaf(pj, __uint_as_float(w.y << 16), a[2]);
                a[3] = fmaf(pj, __uint_as_float(w.y & 0xffff0000u), a[3]);
                a[4] = fmaf(pj, __uint_as_float(w.z << 16), a[4]);
                a[5] = fmaf(pj, __uint_as_float(w.z & 0xffff0000u), a[5]);
                a[6] = fmaf(pj, __uint_as_float(w.w << 16), a[6]);
                a[7] = fmaf(pj, __uint_as_float(w.w & 0xffff0000u), a[7]);
            }
        }
    }

    // merge edge-parity halves (same cols, disjoint edge subsets)
#pragma unroll
    for (int i = 0; i < 8; ++i) a[i] += __shfl_xor(a[i], 32, 64);

    // per-head sum of p, deferred normalization
    psum += __shfl_xor(psum, 8, 64);
    psum += __shfl_xor(psum, 16, 64);
    psum += __shfl_xor(psum, 32, 64);
    const float rs = 1.f / (__shfl(psum, hq, 8) + 1e-9f);
    if (half == 0) {
        const float4 b0 = *(const float4*)&bias[cb];
        const float4 b1 = *(const float4*)&bias[cb + 4];
        *(float4*)&out[(size_t)v * HD + cb] =
            make_float4(fmaf(a[0], rs, b0.x), fmaf(a[1], rs, b0.y),
                        fmaf(a[2], rs, b0.z), fmaf(a[3], rs, b0.w));
        *(float4*)&out[(size_t)v * HD + cb + 4] =
            make_float4(fmaf(a[4], rs, b1.x), fmaf(a[5], rs, b1.y),
                        fmaf(a[6], rs, b1.z), fmaf(a[7], rs, b1.w));
    }
}

extern "C" void kernel_launch(void* const* d_in, const int* in_sizes, int n_in,
                              void* d_out, int out_size, void* d_ws, size_t ws_size,
                              hipStream_t stream) {
    const float* feat     = (const float*)d_in[0];
    const float* edge_emb = (const float*)d_in[1];
    const int*   src      = (const int*)d_in[2];
    const int*   dst      = (const int*)d_in[3];
    const float* W_src    = (const float*)d_in[4];
    const float* W_e      = (const float*)d_in[5];
    const float* attn_l   = (const float*)d_in[6];
    const float* attn_r   = (const float*)d_in[7];
    const float* attn_e   = (const float*)d_in[8];
    const float* bias     = (const float*)d_in[9];
    float* out = (float*)d_out;

    const int N = in_sizes[0] / HD;
    const int E = in_sizes[2];

    char* ws = (char*)d_ws;
    unsigned short* hb = (unsigned short*)ws; ws += (size_t)N * HD * 2;   // 25.6MB
    float* lgcsr = (float*)ws; ws += (size_t)E * H * 4;                   // 25.6MB
    int* src_csr = (int*)ws; ws += (size_t)E * 4;                         // 3.2MB
    int* ord     = (int*)ws; ws += (size_t)E * 4;                         // 3.2MB
    float* el   = (float*)ws; ws += (size_t)N * H * 4;
    float* er   = (float*)ws; ws += (size_t)N * H * 4;
    int*   cnt  = (int*)ws;   ws += (size_t)N * 4;
    int* offs   = (int*)ws; ws += (size_t)(N + 1) * 4;
    unsigned short* Wtb = (unsigned short*)ws; ws += (size_t)HD * HD * 2;
    int* btot  = (int*)ws; ws += 64 * 4;
    float* M   = (float*)ws; ws += 256;

    const int nz  = (N + 255) / 256;
    const int nsb = (N + SCB - 1) / SCB;       // <= 64
    const int bg  = ((N + 15) / 16 + 7) / 8;   // gemm blocks (8 waves each)
    const int bhist = (E + 2047) / 2048;       // histogram blocks

    k0      <<<HD + 1 + nz, 256, 0, stream>>>(W_src, Wtb, W_e, attn_e, M, cnt, N);
    k_fuse  <<<bg + bhist, 512, 0, stream>>>(feat, Wtb, attn_l, attn_r, hb, el, er,
                                             N, bg, dst, cnt, ord, E);
    k_scan1 <<<nsb, SCB, 0, stream>>>(cnt, offs, btot, N);
    k_scan3 <<<nsb, SCB, 0, stream>>>(offs, btot, N, E, nsb);
    k_edge  <<<(E + 255) / 256, 256, 0, stream>>>(src, dst, edge_emb, el, M,
                                                  offs, ord, src_csr, lgcsr, E);
    k_node  <<<(N + 3) / 4, 256, 0, stream>>>(offs, src_csr, lgcsr, er,
                                              hb, bias, out, N);
}